// Round 1
// baseline (1727.456 us; speedup 1.0000x reference)
//
#include <hip/hip_runtime.h>
#include <cstddef>
#include <cstdint>

// BiTreeLSTM forward, bf16-MFMA version — m97-style K-loop.
// DEPTH=17, N_NODES=131071, FEAT=H=512, K=1024 (feats | parent_h).
//
// Combined weight matrix Bt (bf16), stored col-major [col][k], k in [0,1024):
//   col = (u>>4)*96 + ch*16 + (u&15),  ch: 0=px,1=i,2=o,3=f,4=u,5=r, u in [0,512)
//   px chunk rows k>=512 are zero. A 96-col block tile = 16 units x all 6 chunks,
//   so the LSTM gating epilogue is fully in-register per lane.
//
// K-loop structure (this round): BK=64, single-buffered LDS staged via
// global_load_lds width=16 (no VGPR round-trip), 2 barriers per 64-K step,
// XOR-swizzled layout (pre-swizzled global source + swizzled ds_read) so the
// stride-128B fragment reads are bank-conflict-free (2-way max = free).
//
// ws layout:
//   c_all     : N_NODES*512 fp32   (268.4 MB)
//   feats_bf  : N_NODES*512 bf16   (134.2 MB)
//   h_bf      : N_NODES*512 bf16   (134.2 MB)
//   Bt        : 3072*1024  bf16    (6.3 MB)
//   biasC     : 3072 fp32

#define DEPTH   17
#define N_NODES ((1 << DEPTH) - 1)
#define HD      512
#define KD      1024
#define NC      3072

typedef __attribute__((ext_vector_type(8))) short short8;
typedef __attribute__((ext_vector_type(4))) float f32x4;

__device__ __forceinline__ unsigned short f2bf(float x) {
    unsigned u = __builtin_bit_cast(unsigned, x);
    u += 0x7FFFu + ((u >> 16) & 1u);          // round-to-nearest-even
    return (unsigned short)(u >> 16);
}

// fast sigmoid/tanh: __expf + v_rcp, overflow-safe.
__device__ __forceinline__ float fsig(float x) {
    return __builtin_amdgcn_rcpf(1.0f + __expf(-x));
}
__device__ __forceinline__ float ftanh(float x) {
    float e = __expf(-2.0f * fabsf(x));       // in (0,1], never overflows
    float t = (1.0f - e) * __builtin_amdgcn_rcpf(1.0f + e);
    return copysignf(t, x);
}

// async 16B/lane direct global->LDS (wave writes 1024B contiguous at dst)
__device__ __forceinline__ void gl16(const short* g, short* l) {
    __builtin_amdgcn_global_load_lds(
        (const __attribute__((address_space(1))) void*)g,
        (__attribute__((address_space(3))) void*)l, 16, 0, 0);
}

__global__ __launch_bounds__(256) void prep_weights(
    const float* __restrict__ px_w, const float* __restrict__ px_b,
    const float* __restrict__ iofux_w, const float* __restrict__ iofux_b,
    const float* __restrict__ iofuh_w, const float* __restrict__ iofuh_b,
    short* __restrict__ Bt, float* __restrict__ biasC)
{
    int idx = blockIdx.x * 256 + threadIdx.x;       // idx = col*1024 + k
    if (idx < NC * KD) {
        int col = idx >> 10, k = idx & 1023;
        int g = col / 96, rem = col - g * 96;
        int ch = rem >> 4;
        int u = g * 16 + (rem & 15);
        float v;
        if (ch == 0) {
            v = (k < 512) ? px_w[u * 512 + k] : 0.0f;
        } else {
            int q = (ch - 1) * 512 + u;
            v = (k < 512) ? iofux_w[q * 512 + k] : iofuh_w[q * 512 + (k - 512)];
        }
        Bt[idx] = (short)f2bf(v);
    }
    if (idx < NC) {
        int g = idx / 96, rem = idx - g * 96;
        int ch = rem >> 4;
        int u = g * 16 + (rem & 15);
        float b;
        if (ch == 0) b = px_b[u];
        else {
            int q = (ch - 1) * 512 + u;
            b = iofux_b[q] + iofuh_b[q];
        }
        biasC[idx] = b;
    }
}

__global__ __launch_bounds__(256) void conv_feats(
    const float* __restrict__ f, unsigned* __restrict__ o, int n4)
{
    int i = blockIdx.x * 256 + threadIdx.x;
    if (i < n4) {
        float4 v = ((const float4*)f)[i];
        unsigned lo = (unsigned)f2bf(v.x) | ((unsigned)f2bf(v.y) << 16);
        unsigned hi = (unsigned)f2bf(v.z) | ((unsigned)f2bf(v.w) << 16);
        ((uint2*)o)[i] = make_uint2(lo, hi);
    }
}

// One tree level. Grid: (ceil(n/128), 32). Block 256 = 4 waves.
// Block tile: 128 nodes x 96 cols (16 units x 6 chunks). Wave: 32 nodes x 96.
__global__ __launch_bounds__(256) void level_mfma(
    const short* __restrict__ feats_bf,   // N_NODES x 512 bf16
    short* __restrict__ h_bf,             // N_NODES x 512 bf16
    const short* __restrict__ Bt,         // 3072 x 1024 bf16 (col-major)
    const float* __restrict__ biasC,      // 3072
    float* __restrict__ c_all,            // N_NODES x 512 fp32
    float* __restrict__ out,              // N_NODES x 512 fp32 (d_out)
    int level)
{
    const int n      = 1 << level;
    const int start  = n - 1;
    const int startp = (n >> 1) - 1;
    const int mb     = blockIdx.x * 128;
    const int ub     = blockIdx.y;        // 16-unit group, 0..31
    const int t      = threadIdx.x;
    const int wave   = t >> 6;
    const int lane   = t & 63;

    // linear row-major, row stride 64 shorts (128 B); XOR-swizzled content
    __shared__ short As[128 * 64];        // 16 KB
    __shared__ short Bs[96 * 64];         // 12 KB

    f32x4 acc[2][6];
#pragma unroll
    for (int a = 0; a < 2; ++a)
#pragma unroll
        for (int b = 0; b < 6; ++b) acc[a][b] = (f32x4)(0.0f);

    // ---- staging geometry -------------------------------------------------
    // One gl16 call = 1024 B = 8 tile-rows x 128 B. Lane l writes physical
    // LDS 16B-slot (row 8c+(l>>3), slot l&7); the data that belongs there is
    // source chunk (l&7)^(l>>3) (inverse of the read-side XOR swizzle).
    const int sub = lane >> 3;                   // 0..7: row within 8-row group
    const int kx  = ((lane & 7) ^ sub) * 8;      // pre-swizzled short offset

    const short* aF[4];
    const short* aH[4];
    short*       aDst[4];
#pragma unroll
    for (int i = 0; i < 4; ++i) {
        int c  = wave * 4 + i;                   // A call index 0..15
        int r  = c * 8 + sub;                    // tile row 0..127
        int nd = mb + r; if (nd > n - 1) nd = n - 1;
        aF[i]   = feats_bf + (size_t)(start + nd) * HD + kx;
        aH[i]   = h_bf + (size_t)(startp + (nd >> 1)) * HD + kx;
        aDst[i] = &As[c * 512];
    }
    const short* bSrc[3];
    short*       bDst[3];
#pragma unroll
    for (int i = 0; i < 3; ++i) {
        int c  = wave * 3 + i;                   // B call index 0..11
        int bc = c * 8 + sub;                    // tile col 0..95
        bSrc[i] = Bt + ((size_t)(ub * 96 + bc) << 10) + kx;
        bDst[i] = &Bs[c * 512];
    }

    // ---- fragment-read offsets (shorts), same XOR swizzle -----------------
    // A frag: lane holds A[row=lane&15][k=(lane>>4)*8 ..+8]; rows stride 128B.
    // swizzle value depends only on (row&7) == (lane&7) for all our reads.
    const int m16 = lane & 15;
    const int q   = lane >> 4;
    const int sw  = (lane & 7) << 4;             // byte swizzle, bits 4..6
    const int cs0 = ((q * 16) ^ sw) >> 1;        // k-slice 0 short offset
    const int cs1 = ((q * 16 + 64) ^ sw) >> 1;   // k-slice 1 short offset

    const int kend = (level == 0) ? 512 : KD;

    for (int k0 = 0; k0 < kend; k0 += 64) {
        __syncthreads();                          // previous tile fully read
        if (k0 < 512) {
#pragma unroll
            for (int i = 0; i < 4; ++i) gl16(aF[i] + k0, aDst[i]);
        } else {
#pragma unroll
            for (int i = 0; i < 4; ++i) gl16(aH[i] + (k0 - 512), aDst[i]);
        }
#pragma unroll
        for (int i = 0; i < 3; ++i) gl16(bSrc[i] + k0, bDst[i]);
        __syncthreads();                          // vmcnt drained -> data ready

#pragma unroll
        for (int s = 0; s < 2; ++s) {
            const int cs = s ? cs1 : cs0;
            short8 a0 = *(const short8*)&As[(wave * 32 + m16) * 64 + cs];
            short8 a1 = *(const short8*)&As[(wave * 32 + 16 + m16) * 64 + cs];
#pragma unroll
            for (int ch = 0; ch < 6; ++ch) {
                short8 bf = *(const short8*)&Bs[(ch * 16 + m16) * 64 + cs];
                acc[0][ch] = __builtin_amdgcn_mfma_f32_16x16x32_bf16(a0, bf, acc[0][ch], 0, 0, 0);
                acc[1][ch] = __builtin_amdgcn_mfma_f32_16x16x32_bf16(a1, bf, acc[1][ch], 0, 0, 0);
            }
        }
    }

    // ---- fused gating epilogue (C/D layout: col=lane&15, row=(lane>>4)*4+reg)
    const int l15 = lane & 15, qr = lane >> 4;
    const float b0 = biasC[ub * 96 +       l15];
    const float b1 = biasC[ub * 96 + 16  + l15];
    const float b2 = biasC[ub * 96 + 32  + l15];
    const float b3 = biasC[ub * 96 + 48  + l15];
    const float b4 = biasC[ub * 96 + 64  + l15];
    const float b5 = biasC[ub * 96 + 80  + l15];
    const int uglob = ub * 16 + l15;

#pragma unroll
    for (int mt = 0; mt < 2; ++mt) {
        int j0 = mb + wave * 32 + mt * 16 + qr * 4;
#pragma unroll
        for (int r = 0; r < 4; ++r) {
            int j = j0 + r;
            if (j < n) {
                float px = acc[mt][0][r] + b0;
                float gi = fsig(acc[mt][1][r] + b1);
                float go = fsig(acc[mt][2][r] + b2);
                float gf = fsig(acc[mt][3][r] + b3);
                float gu = ftanh(acc[mt][4][r] + b4);
                float gr = fsig(acc[mt][5][r] + b5);
                float pc = (level > 0)
                    ? c_all[(size_t)(startp + (j >> 1)) * HD + uglob] : 0.0f;
                float cc = gi * gu + gf * pc;
                float hh = go * ftanh(cc);
                float hf = gr * hh + (1.0f - gr) * px;
                size_t off = (size_t)(start + j) * HD + uglob;
                c_all[off] = cc;
                out[off]   = hf;
                h_bf[off]  = (short)f2bf(hf);
            }
        }
    }
}

extern "C" void kernel_launch(void* const* d_in, const int* in_sizes, int n_in,
                              void* d_out, int out_size, void* d_ws, size_t ws_size,
                              hipStream_t stream)
{
    const float* features = (const float*)d_in[0];
    const float* px_w     = (const float*)d_in[1];
    const float* px_b     = (const float*)d_in[2];
    const float* iofux_w  = (const float*)d_in[3];
    const float* iofux_b  = (const float*)d_in[4];
    const float* iofuh_w  = (const float*)d_in[5];
    const float* iofuh_b  = (const float*)d_in[6];
    float* out = (float*)d_out;

    float* c_all    = (float*)d_ws;
    short* feats_bf = (short*)(c_all + (size_t)N_NODES * HD);
    short* h_bf     = feats_bf + (size_t)N_NODES * HD;
    short* Bt       = h_bf + (size_t)N_NODES * HD;
    float* biasC    = (float*)(Bt + (size_t)NC * KD);

    {
        int total = NC * KD;
        prep_weights<<<(total + 255) / 256, 256, 0, stream>>>(
            px_w, px_b, iofux_w, iofux_b, iofuh_w, iofuh_b, Bt, biasC);
    }
    {
        int n4 = (N_NODES * HD) / 4;   // 512 divisible by 4
        conv_feats<<<(n4 + 255) / 256, 256, 0, stream>>>(
            features, (unsigned*)feats_bf, n4);
    }
    for (int d = 0; d < DEPTH; ++d) {
        int n = 1 << d;
        dim3 grid((n + 127) / 128, 32);
        level_mfma<<<grid, 256, 0, stream>>>(
            feats_bf, h_bf, Bt, biasC, c_all, out, d);
    }
}

// Round 3
// 1677.271 us; speedup vs baseline: 1.0299x; 1.0299x over previous
//
#include <hip/hip_runtime.h>
#include <cstddef>
#include <cstdint>

// BiTreeLSTM forward, bf16-MFMA version — double-buffered K-loop.
// DEPTH=17, N_NODES=131071, FEAT=H=512, K=1024 (feats | parent_h).
//
// Combined weight matrix Bt (bf16), stored col-major [col][k], k in [0,1024):
//   col = (u>>4)*96 + ch*16 + (u&15),  ch: 0=px,1=i,2=o,3=f,4=u,5=r, u in [0,512)
//   px chunk rows k>=512 are zero. A 96-col group = 16 units x all 6 chunks,
//   so the LSTM gating epilogue is fully in-register per lane.
//
// This round (resubmit — round-2 bench was an infra failure, kernel never ran):
// block tile 128 nodes x 192 cols (2 col-groups), 512 threads
// (8 waves: 4 node-quadrants x 2 col-halves), BK=64, DOUBLE-buffered LDS
// staged via global_load_lds width=16, ONE barrier per K-step (prefetch
// issued before compute, so the vmcnt(0) drain at the barrier lands after
// the MFMAs). XOR-swizzled LDS (pre-swizzled global source + swizzled
// ds_read) keeps the stride-128B fragment reads conflict-free.
//
// ws layout:
//   c_all     : N_NODES*512 fp32   (268.4 MB)
//   feats_bf  : N_NODES*512 bf16   (134.2 MB)
//   h_bf      : N_NODES*512 bf16   (134.2 MB)
//   Bt        : 3072*1024  bf16    (6.3 MB)
//   biasC     : 3072 fp32

#define DEPTH   17
#define N_NODES ((1 << DEPTH) - 1)
#define HD      512
#define KD      1024
#define NC      3072
#define MTI     128     // nodes per block
#define NTI     192     // cols per block
#define NUB     16      // 3072 / NTI

typedef __attribute__((ext_vector_type(8))) short short8;
typedef __attribute__((ext_vector_type(4))) float f32x4;

__device__ __forceinline__ unsigned short f2bf(float x) {
    unsigned u = __builtin_bit_cast(unsigned, x);
    u += 0x7FFFu + ((u >> 16) & 1u);          // round-to-nearest-even
    return (unsigned short)(u >> 16);
}

// fast sigmoid/tanh: __expf + v_rcp, overflow-safe.
__device__ __forceinline__ float fsig(float x) {
    return __builtin_amdgcn_rcpf(1.0f + __expf(-x));
}
__device__ __forceinline__ float ftanh(float x) {
    float e = __expf(-2.0f * fabsf(x));       // in (0,1], never overflows
    float t = (1.0f - e) * __builtin_amdgcn_rcpf(1.0f + e);
    return copysignf(t, x);
}

// async 16B/lane direct global->LDS (wave writes 1024B contiguous at dst)
__device__ __forceinline__ void gl16(const short* g, short* l) {
    __builtin_amdgcn_global_load_lds(
        (const __attribute__((address_space(1))) void*)g,
        (__attribute__((address_space(3))) void*)l, 16, 0, 0);
}

__global__ __launch_bounds__(256) void prep_weights(
    const float* __restrict__ px_w, const float* __restrict__ px_b,
    const float* __restrict__ iofux_w, const float* __restrict__ iofux_b,
    const float* __restrict__ iofuh_w, const float* __restrict__ iofuh_b,
    short* __restrict__ Bt, float* __restrict__ biasC)
{
    int idx = blockIdx.x * 256 + threadIdx.x;       // idx = col*1024 + k
    if (idx < NC * KD) {
        int col = idx >> 10, k = idx & 1023;
        int g = col / 96, rem = col - g * 96;
        int ch = rem >> 4;
        int u = g * 16 + (rem & 15);
        float v;
        if (ch == 0) {
            v = (k < 512) ? px_w[u * 512 + k] : 0.0f;
        } else {
            int q = (ch - 1) * 512 + u;
            v = (k < 512) ? iofux_w[q * 512 + k] : iofuh_w[q * 512 + (k - 512)];
        }
        Bt[idx] = (short)f2bf(v);
    }
    if (idx < NC) {
        int g = idx / 96, rem = idx - g * 96;
        int ch = rem >> 4;
        int u = g * 16 + (rem & 15);
        float b;
        if (ch == 0) b = px_b[u];
        else {
            int q = (ch - 1) * 512 + u;
            b = iofux_b[q] + iofuh_b[q];
        }
        biasC[idx] = b;
    }
}

__global__ __launch_bounds__(256) void conv_feats(
    const float* __restrict__ f, unsigned* __restrict__ o, int n4)
{
    int i = blockIdx.x * 256 + threadIdx.x;
    if (i < n4) {
        float4 v = ((const float4*)f)[i];
        unsigned lo = (unsigned)f2bf(v.x) | ((unsigned)f2bf(v.y) << 16);
        unsigned hi = (unsigned)f2bf(v.z) | ((unsigned)f2bf(v.w) << 16);
        ((uint2*)o)[i] = make_uint2(lo, hi);
    }
}

// One tree level. Grid: (ceil(n/128), 16). Block 512 = 8 waves.
// Block tile: 128 nodes x 192 cols. Wave: 32 nodes x 96 cols.
__global__ __launch_bounds__(512) void level_mfma(
    const short* __restrict__ feats_bf,   // N_NODES x 512 bf16
    short* __restrict__ h_bf,             // N_NODES x 512 bf16
    const short* __restrict__ Bt,         // 3072 x 1024 bf16 (col-major)
    const float* __restrict__ biasC,      // 3072
    float* __restrict__ c_all,            // N_NODES x 512 fp32
    float* __restrict__ out,              // N_NODES x 512 fp32 (d_out)
    int level)
{
    const int n      = 1 << level;
    const int start  = n - 1;
    const int startp = (n >> 1) - 1;
    const int mb     = blockIdx.x * MTI;
    const int ub     = blockIdx.y;        // col-group pair, 0..15
    const int t      = threadIdx.x;
    const int wave   = t >> 6;
    const int lane   = t & 63;
    const int wr     = wave & 3;          // node quadrant (32 rows)
    const int wc     = wave >> 2;         // col half (96 cols)

    // linear row-major, row stride 64 shorts (128 B); XOR-swizzled content
    __shared__ short As[2][MTI * 64];     // 2 x 16 KB
    __shared__ short Bs[2][NTI * 64];     // 2 x 24 KB

    f32x4 acc[2][6];
#pragma unroll
    for (int a = 0; a < 2; ++a)
#pragma unroll
        for (int b = 0; b < 6; ++b) acc[a][b] = (f32x4)(0.0f);

    // ---- staging geometry -------------------------------------------------
    // One gl16 call = 1024 B = 8 tile-rows x 128 B. Lane l writes physical
    // LDS 16B-slot (row 8c+(l>>3), slot l&7); the data that belongs there is
    // source chunk (l&7)^(l>>3) (inverse of the read-side XOR swizzle).
    const int sub = lane >> 3;                   // 0..7: row within 8-row group
    const int kx  = ((lane & 7) ^ sub) * 8;      // pre-swizzled short offset

    const short* aF[2];
    const short* aH[2];
    int aC[2];
#pragma unroll
    for (int i = 0; i < 2; ++i) {
        int c  = wave * 2 + i;                   // A call index 0..15
        int r  = c * 8 + sub;                    // tile row 0..127
        int nd = mb + r; if (nd > n - 1) nd = n - 1;
        aF[i] = feats_bf + (size_t)(start + nd) * HD + kx;
        aH[i] = h_bf + (size_t)(startp + (nd >> 1)) * HD + kx;
        aC[i] = c * 512;                         // short offset into As[buf]
    }
    const short* bS[3];
    int bC[3];
#pragma unroll
    for (int i = 0; i < 3; ++i) {
        int c  = wave * 3 + i;                   // B call index 0..23
        int bc = c * 8 + sub;                    // tile col 0..191
        bS[i] = Bt + ((size_t)(ub * NTI + bc) << 10) + kx;
        bC[i] = c * 512;
    }

    // ---- fragment-read offsets (shorts), same XOR swizzle -----------------
    // A frag: lane holds A[row=lane&15][k=(lane>>4)*8 ..+8]; rows stride 128B.
    // swizzle value depends only on (row&7) == (lane&7) for all our reads.
    const int m16 = lane & 15;
    const int q   = lane >> 4;
    const int sw  = (lane & 7) << 4;             // byte swizzle, bits 4..6
    const int cs0 = ((q * 16) ^ sw) >> 1;        // k-slice 0 short offset
    const int cs1 = ((q * 16 + 64) ^ sw) >> 1;   // k-slice 1 short offset

    const int kend = (level == 0) ? 512 : KD;

    // ---- prologue: stage k0=0 into buf 0 ----------------------------------
#pragma unroll
    for (int i = 0; i < 2; ++i) gl16(aF[i], &As[0][aC[i]]);
#pragma unroll
    for (int i = 0; i < 3; ++i) gl16(bS[i], &Bs[0][bC[i]]);
    asm volatile("s_waitcnt vmcnt(0)" ::: "memory");
    __syncthreads();

    int cur = 0;
    for (int k0 = 0; k0 < kend; k0 += 64) {
        const int nk = k0 + 64;
        if (nk < kend) {            // issue next tile BEFORE computing current
            if (nk < 512) {
#pragma unroll
                for (int i = 0; i < 2; ++i) gl16(aF[i] + nk, &As[cur ^ 1][aC[i]]);
            } else {
#pragma unroll
                for (int i = 0; i < 2; ++i) gl16(aH[i] + (nk - 512), &As[cur ^ 1][aC[i]]);
            }
#pragma unroll
            for (int i = 0; i < 3; ++i) gl16(bS[i] + nk, &Bs[cur ^ 1][bC[i]]);
        }

#pragma unroll
        for (int s = 0; s < 2; ++s) {
            const int cs = s ? cs1 : cs0;
            short8 a0 = *(const short8*)&As[cur][(wr * 32 + m16) * 64 + cs];
            short8 a1 = *(const short8*)&As[cur][(wr * 32 + 16 + m16) * 64 + cs];
#pragma unroll
            for (int ch = 0; ch < 6; ++ch) {
                short8 bf = *(const short8*)&Bs[cur][(wc * 96 + ch * 16 + m16) * 64 + cs];
                acc[0][ch] = __builtin_amdgcn_mfma_f32_16x16x32_bf16(a0, bf, acc[0][ch], 0, 0, 0);
                acc[1][ch] = __builtin_amdgcn_mfma_f32_16x16x32_bf16(a1, bf, acc[1][ch], 0, 0, 0);
            }
        }

        __syncthreads();   // drains vmcnt -> next buffer ready; readers done
        cur ^= 1;
    }

    // ---- fused gating epilogue (C/D layout: col=lane&15, row=(lane>>4)*4+reg)
    const int l15 = lane & 15, qr = lane >> 4;
    const int bb = (ub * 2 + wc) * 96;
    const float b0 = biasC[bb +       l15];
    const float b1 = biasC[bb + 16  + l15];
    const float b2 = biasC[bb + 32  + l15];
    const float b3 = biasC[bb + 48  + l15];
    const float b4 = biasC[bb + 64  + l15];
    const float b5 = biasC[bb + 80  + l15];
    const int uglob = ub * 32 + wc * 16 + l15;

#pragma unroll
    for (int mt = 0; mt < 2; ++mt) {
        int j0 = mb + wr * 32 + mt * 16 + qr * 4;
#pragma unroll
        for (int r = 0; r < 4; ++r) {
            int j = j0 + r;
            if (j < n) {
                float px = acc[mt][0][r] + b0;
                float gi = fsig(acc[mt][1][r] + b1);
                float go = fsig(acc[mt][2][r] + b2);
                float gf = fsig(acc[mt][3][r] + b3);
                float gu = ftanh(acc[mt][4][r] + b4);
                float gr = fsig(acc[mt][5][r] + b5);
                float pc = (level > 0)
                    ? c_all[(size_t)(startp + (j >> 1)) * HD + uglob] : 0.0f;
                float cc = gi * gu + gf * pc;
                float hh = go * ftanh(cc);
                float hf = gr * hh + (1.0f - gr) * px;
                size_t off = (size_t)(start + j) * HD + uglob;
                c_all[off] = cc;
                out[off]   = hf;
                h_bf[off]  = (short)f2bf(hf);
            }
        }
    }
}

extern "C" void kernel_launch(void* const* d_in, const int* in_sizes, int n_in,
                              void* d_out, int out_size, void* d_ws, size_t ws_size,
                              hipStream_t stream)
{
    const float* features = (const float*)d_in[0];
    const float* px_w     = (const float*)d_in[1];
    const float* px_b     = (const float*)d_in[2];
    const float* iofux_w  = (const float*)d_in[3];
    const float* iofux_b  = (const float*)d_in[4];
    const float* iofuh_w  = (const float*)d_in[5];
    const float* iofuh_b  = (const float*)d_in[6];
    float* out = (float*)d_out;

    float* c_all    = (float*)d_ws;
    short* feats_bf = (short*)(c_all + (size_t)N_NODES * HD);
    short* h_bf     = feats_bf + (size_t)N_NODES * HD;
    short* Bt       = h_bf + (size_t)N_NODES * HD;
    float* biasC    = (float*)(Bt + (size_t)NC * KD);

    {
        int total = NC * KD;
        prep_weights<<<(total + 255) / 256, 256, 0, stream>>>(
            px_w, px_b, iofux_w, iofux_b, iofuh_w, iofuh_b, Bt, biasC);
    }
    {
        int n4 = (N_NODES * HD) / 4;   // 512 divisible by 4
        conv_feats<<<(n4 + 255) / 256, 256, 0, stream>>>(
            features, (unsigned*)feats_bf, n4);
    }
    for (int d = 0; d < DEPTH; ++d) {
        int n = 1 << d;
        dim3 grid((n + MTI - 1) / MTI, NUB);
        level_mfma<<<grid, 512, 0, stream>>>(
            feats_bf, h_bf, Bt, biasC, c_all, out, d);
    }
}